// Round 2
// baseline (2755.059 us; speedup 1.0000x reference)
//
#include <hip/hip_runtime.h>

// WaveNet residual stack, fp32 baseline.
// 16 blocks, dilations [1,2,4,...,128] x2. C=64 res ch, S=128 skip ch.
// Per-layer kernel; state ping-pong in d_ws (needs 2*16*64*8192*4 = 67.1 MB).
// Skip accumulator lives directly in d_out's skip region (layer 0 writes,
// layers 1..15 RMW; kernels on same stream are ordered).

#define NBATCH 16
#define C 64
#define SC 128
#define L0 8192
#define OSIZE 7682
#define TILE 64
#define PAD 4   // row stride 68 words: 16B-aligned rows, modest conflict cost

__global__ __launch_bounds__(256) void wavenet_layer(
    const float* __restrict__ src, int src_stride, int Lin,
    float* __restrict__ dst, int dst_stride,
    const float* __restrict__ Wd,   // [64][64][2]
    const float* __restrict__ Wr,   // [64][64]
    const float* __restrict__ Ws,   // [128][64]
    float* __restrict__ skip,       // [N][128][OSIZE]
    int d, int skip_init)
{
    const int Lout = Lin - d;
    const int n  = blockIdx.y;
    const int l0 = blockIdx.x * TILE;
    if (l0 >= Lout) return;
    const int np = min(TILE, Lout - l0);

    __shared__ float sl[C][TILE + PAD];  // src[:, l0+p]      (left tap)
    __shared__ float sr[C][TILE + PAD];  // src[:, l0+p+d]    (right tap = residual src)
    __shared__ float sg[C][TILE + PAD];  // gated activation

    const int t = threadIdx.x;

    // ---- stage taps: coalesced (p fast-varying across lanes) ----
    for (int idx = t; idx < C * TILE; idx += 256) {
        int k = idx >> 6;
        int p = idx & 63;
        float vl = 0.f, vr = 0.f;
        if (p < np) {
            const float* row = src + (size_t)(n * C + k) * src_stride;
            vl = row[l0 + p];
            vr = row[l0 + p + d];
        }
        sl[k][p] = vl;
        sr[k][p] = vr;
    }
    __syncthreads();

    const int oc0 = (t >> 4) << 2;   // 4 out-channels per thread
    const int p0  = (t & 15) << 2;   // 4 positions per thread

    // ---- phase 1: dilated conv (K=64, 2 taps) + gated activation ----
    {
        float acc[4][4] = {};
        for (int k = 0; k < C; ++k) {
            float a[4], b[4];
            #pragma unroll
            for (int pp = 0; pp < 4; ++pp) { a[pp] = sl[k][p0 + pp]; b[pp] = sr[k][p0 + pp]; }
            #pragma unroll
            for (int oo = 0; oo < 4; ++oo) {
                float w0 = Wd[(((oc0 + oo) * C + k) << 1) + 0];
                float w1 = Wd[(((oc0 + oo) * C + k) << 1) + 1];
                #pragma unroll
                for (int pp = 0; pp < 4; ++pp)
                    acc[oo][pp] = fmaf(w0, a[pp], fmaf(w1, b[pp], acc[oo][pp]));
            }
        }
        #pragma unroll
        for (int oo = 0; oo < 4; ++oo) {
            #pragma unroll
            for (int pp = 0; pp < 4; ++pp) {
                float y  = acc[oo][pp];
                float e2 = __expf(2.f * y);
                float th = 1.f - 2.f / (e2 + 1.f);          // tanh(y)
                float sg_ = 1.f / (1.f + __expf(-y));       // sigmoid(y)
                sg[oc0 + oo][p0 + pp] = th * sg_;
            }
        }
    }
    __syncthreads();

    // ---- phase 2a: res = Wr @ g + src[:, l+d] ----
    {
        float acc[4][4] = {};
        for (int k = 0; k < C; ++k) {
            float gv[4];
            #pragma unroll
            for (int pp = 0; pp < 4; ++pp) gv[pp] = sg[k][p0 + pp];
            #pragma unroll
            for (int oo = 0; oo < 4; ++oo) {
                float w = Wr[(oc0 + oo) * C + k];
                #pragma unroll
                for (int pp = 0; pp < 4; ++pp)
                    acc[oo][pp] = fmaf(w, gv[pp], acc[oo][pp]);
            }
        }
        #pragma unroll
        for (int oo = 0; oo < 4; ++oo) {
            #pragma unroll
            for (int pp = 0; pp < 4; ++pp) {
                int p = p0 + pp;
                if (p < np)
                    dst[(size_t)(n * C + oc0 + oo) * dst_stride + l0 + p]
                        = acc[oo][pp] + sr[oc0 + oo][p];
            }
        }
    }

    // ---- phase 2b: skip += Ws @ g, right-aligned into [OSIZE] window ----
    {
        const int sbase = Lout - OSIZE;   // skip slot j = l - sbase, l >= sbase
        if (l0 + TILE > sbase) {
            const int sc0 = (t >> 4) << 3;   // 8 skip-channels per thread
            float acc[8][4] = {};
            for (int k = 0; k < C; ++k) {
                float gv[4];
                #pragma unroll
                for (int pp = 0; pp < 4; ++pp) gv[pp] = sg[k][p0 + pp];
                #pragma unroll
                for (int ss = 0; ss < 8; ++ss) {
                    float w = Ws[(sc0 + ss) * C + k];
                    #pragma unroll
                    for (int pp = 0; pp < 4; ++pp)
                        acc[ss][pp] = fmaf(w, gv[pp], acc[ss][pp]);
                }
            }
            #pragma unroll
            for (int ss = 0; ss < 8; ++ss) {
                #pragma unroll
                for (int pp = 0; pp < 4; ++pp) {
                    int l = l0 + p0 + pp;
                    if (l >= sbase && l < Lout) {
                        size_t idx = (size_t)(n * SC + sc0 + ss) * OSIZE + (l - sbase);
                        if (skip_init) skip[idx] = acc[ss][pp];
                        else           skip[idx] += acc[ss][pp];
                    }
                }
            }
        }
    }
}

extern "C" void kernel_launch(void* const* d_in, const int* in_sizes, int n_in,
                              void* d_out, int out_size, void* d_ws, size_t ws_size,
                              hipStream_t stream) {
    const float* x      = (const float*)d_in[0];
    const float* W_dil  = (const float*)d_in[1];   // [16][64][64][2]
    const float* W_res  = (const float*)d_in[2];   // [16][64][64]
    const float* W_skip = (const float*)d_in[3];   // [16][128][64]

    float* out  = (float*)d_out;                       // [16][64][7682]
    float* skip = out + (size_t)NBATCH * C * OSIZE;    // [16][128][7682]

    float* bufA = (float*)d_ws;                        // 33.6 MB
    float* bufB = bufA + (size_t)NBATCH * C * L0;      // 33.6 MB

    const float* src = x;
    int src_stride = L0;
    int Lin = L0;
    float* bufs[2] = {bufA, bufB};

    for (int i = 0; i < 16; ++i) {
        int d    = 1 << (i & 7);
        int Lout = Lin - d;
        float* dst;
        int dst_stride;
        if (i == 15) { dst = out;         dst_stride = OSIZE; }
        else         { dst = bufs[i & 1]; dst_stride = L0;    }

        dim3 grid((Lout + TILE - 1) / TILE, NBATCH);
        wavenet_layer<<<grid, 256, 0, stream>>>(
            src, src_stride, Lin, dst, dst_stride,
            W_dil + (size_t)i * C * C * 2,
            W_res + (size_t)i * C * C,
            W_skip + (size_t)i * SC * C,
            skip, d, (i == 0) ? 1 : 0);

        src = dst;
        src_stride = dst_stride;
        Lin = Lout;
    }
}

// Round 3
// 2427.007 us; speedup vs baseline: 1.1352x; 1.1352x over previous
//
#include <hip/hip_runtime.h>

// WaveNet residual stack, fp32, wave-uniform-weight layout.
// lane = position (64), wave = out-channel group. Weight indices are
// wave-uniform (readfirstlane) -> scalar s_load broadcasts; LDS accesses
// stride-1 -> conflict-free. 16 blocks, dilations [1..128]x2.
// State ping-pong in d_ws; skip accumulates in d_out's skip region
// (layer 0 init-writes, layers 1..15 RMW; same-stream ordering).

#define NBATCH 16
#define C 64
#define SC 128
#define L0 8192
#define OSIZE 7682
#define TILE 64

__global__ __launch_bounds__(256, 3) void wavenet_layer(
    const float* __restrict__ src, int src_stride, int Lin,
    float* __restrict__ dst, int dst_stride,
    const float* __restrict__ Wd,   // [64][64][2]
    const float* __restrict__ Wr,   // [64][64]
    const float* __restrict__ Ws,   // [128][64]
    float* __restrict__ skip,       // [N][128][OSIZE]
    int d, int skip_init)
{
    const int Lout = Lin - d;
    const int n  = blockIdx.y;
    const int l0 = blockIdx.x * TILE;
    if (l0 >= Lout) return;
    const int np = min(TILE, Lout - l0);

    __shared__ float sl[C][TILE];   // src[:, l0+p]    (left tap)
    __shared__ float sr[C][TILE];   // src[:, l0+p+d]  (right tap = residual src)
    __shared__ float sg[C][TILE];   // gated activation

    const int t    = threadIdx.x;
    const int lane = t & 63;
    const int wv   = __builtin_amdgcn_readfirstlane(t >> 6);  // wave id 0..3, uniform

    // ---- stage taps: coalesced, stride-1 LDS writes ----
    for (int idx = t; idx < C * TILE; idx += 256) {
        int k = idx >> 6;
        int p = idx & 63;
        float vl = 0.f, vr = 0.f;
        if (p < np) {
            const float* row = src + (size_t)(n * C + k) * src_stride + l0 + p;
            vl = row[0];
            vr = row[d];
        }
        sl[k][p] = vl;
        sr[k][p] = vr;
    }
    __syncthreads();

    const int oc0 = wv * 16;        // this wave's 16 res channels

    // ---- phase 1: dilated conv (2 taps, K=64) + gated activation ----
    float acc[16];
    #pragma unroll
    for (int i = 0; i < 16; ++i) acc[i] = 0.f;
    for (int k = 0; k < C; ++k) {
        float a = sl[k][lane];
        float b = sr[k][lane];
        const float* wrow = Wd + ((size_t)oc0 * C + k) * 2;   // uniform -> s_load
        #pragma unroll
        for (int oo = 0; oo < 16; ++oo) {
            float w0 = wrow[oo * C * 2];
            float w1 = wrow[oo * C * 2 + 1];
            acc[oo] = fmaf(w0, a, fmaf(w1, b, acc[oo]));
        }
    }
    #pragma unroll
    for (int oo = 0; oo < 16; ++oo) {
        // tanh(y)*sigmoid(y) = u(u-1)/(u^2+1), u = e^y. Saturates by |y|~10.
        float y = fminf(fmaxf(acc[oo], -20.f), 20.f);
        float u = __expf(y);
        float g = u * (u - 1.f) / fmaf(u, u, 1.f);
        sg[oc0 + oo][lane] = g;
    }
    __syncthreads();

    // ---- phase 2a: res = Wr @ g + src[:, l+d] ----
    #pragma unroll
    for (int i = 0; i < 16; ++i) acc[i] = 0.f;
    for (int k = 0; k < C; ++k) {
        float gv = sg[k][lane];
        const float* wrow = Wr + (size_t)oc0 * C + k;         // uniform -> s_load
        #pragma unroll
        for (int oo = 0; oo < 16; ++oo)
            acc[oo] = fmaf(wrow[oo * C], gv, acc[oo]);
    }
    if (lane < np) {
        #pragma unroll
        for (int oo = 0; oo < 16; ++oo)
            dst[(size_t)(n * C + oc0 + oo) * dst_stride + l0 + lane]
                = acc[oo] + sr[oc0 + oo][lane];
    }

    // ---- phase 2b: skip += Ws @ g, right-aligned [OSIZE] window ----
    const int sbase = Lout - OSIZE;     // skip slot j = l - sbase
    if (l0 + TILE > sbase) {
        const int sc0 = wv * 32;        // this wave's 32 skip channels
        float sa[32];
        #pragma unroll
        for (int i = 0; i < 32; ++i) sa[i] = 0.f;
        for (int k = 0; k < C; ++k) {
            float gv = sg[k][lane];
            const float* wrow = Ws + (size_t)sc0 * C + k;     // uniform -> s_load
            #pragma unroll
            for (int ss = 0; ss < 32; ++ss)
                sa[ss] = fmaf(wrow[ss * C], gv, sa[ss]);
        }
        int l = l0 + lane;
        if (l >= sbase && l < Lout) {
            size_t base = (size_t)(n * SC + sc0) * OSIZE + (l - sbase);
            if (skip_init) {
                #pragma unroll
                for (int ss = 0; ss < 32; ++ss)
                    skip[base + (size_t)ss * OSIZE] = sa[ss];
            } else {
                #pragma unroll
                for (int ss = 0; ss < 32; ++ss)
                    skip[base + (size_t)ss * OSIZE] += sa[ss];
            }
        }
    }
}

extern "C" void kernel_launch(void* const* d_in, const int* in_sizes, int n_in,
                              void* d_out, int out_size, void* d_ws, size_t ws_size,
                              hipStream_t stream) {
    const float* x      = (const float*)d_in[0];
    const float* W_dil  = (const float*)d_in[1];   // [16][64][64][2]
    const float* W_res  = (const float*)d_in[2];   // [16][64][64]
    const float* W_skip = (const float*)d_in[3];   // [16][128][64]

    float* out  = (float*)d_out;                       // [16][64][7682]
    float* skip = out + (size_t)NBATCH * C * OSIZE;    // [16][128][7682]

    float* bufA = (float*)d_ws;                        // 33.6 MB
    float* bufB = bufA + (size_t)NBATCH * C * L0;      // 33.6 MB

    const float* src = x;
    int src_stride = L0;
    int Lin = L0;
    float* bufs[2] = {bufA, bufB};

    for (int i = 0; i < 16; ++i) {
        int d    = 1 << (i & 7);
        int Lout = Lin - d;
        float* dst;
        int dst_stride;
        if (i == 15) { dst = out;         dst_stride = OSIZE; }
        else         { dst = bufs[i & 1]; dst_stride = L0;    }

        dim3 grid((Lout + TILE - 1) / TILE, NBATCH);
        wavenet_layer<<<grid, 256, 0, stream>>>(
            src, src_stride, Lin, dst, dst_stride,
            W_dil + (size_t)i * C * C * 2,
            W_res + (size_t)i * C * C,
            W_skip + (size_t)i * SC * C,
            skip, d, (i == 0) ? 1 : 0);

        src = dst;
        src_stride = dst_stride;
        Lin = Lout;
    }
}

// Round 4
// 1760.423 us; speedup vs baseline: 1.5650x; 1.3786x over previous
//
#include <hip/hip_runtime.h>

// WaveNet residual stack, fp32, k-major transposed weights.
// lane = position (64), wave = out-channel group (uniform weight indices ->
// contiguous wide s_loads after k-major transpose). Unified dilated staging
// buffer sx[C][64+d] in dynamic LDS; gate buffer aliases dead prefix when
// d >= 64. State ping-pong in d_ws; skip accumulates in d_out's skip region.

#define NBATCH 16
#define C 64
#define SC 128
#define L0 8192
#define OSIZE 7682
#define TILE 64

// --- pre-pass: k-major weight transpose into workspace (1.3 MB) ---
// Wd[16][64][64][2] (ly,o,k,tap) -> Wdt[16][64][2][64] (ly,k,tap,o)
// Wr[16][64][64]    (ly,o,k)     -> Wrt[16][64][64]    (ly,k,o)
// Ws[16][128][64]   (ly,s,k)     -> Wst[16][64][128]   (ly,k,s)
__global__ __launch_bounds__(256) void transpose_weights(
    const float* __restrict__ Wd, const float* __restrict__ Wr,
    const float* __restrict__ Ws,
    float* __restrict__ Wdt, float* __restrict__ Wrt, float* __restrict__ Wst)
{
    int idx = blockIdx.x * 256 + threadIdx.x;
    if (idx < 131072) {                    // Wdt
        int o = idx & 63, tap = (idx >> 6) & 1, k = (idx >> 7) & 63, ly = idx >> 13;
        Wdt[idx] = Wd[(((ly * 64 + o) * 64 + k) << 1) + tap];
    } else if (idx < 196608) {             // Wrt
        int j = idx - 131072;
        int o = j & 63, k = (j >> 6) & 63, ly = j >> 12;
        Wrt[j] = Wr[(ly * 64 + o) * 64 + k];
    } else if (idx < 327680) {             // Wst
        int j = idx - 196608;
        int s = j & 127, k = (j >> 7) & 63, ly = j >> 13;
        Wst[j] = Ws[(ly * 128 + s) * 64 + k];
    }
}

__global__ __launch_bounds__(256, 4) void wavenet_layer(
    const float* __restrict__ src, int src_stride, int Lin,
    float* __restrict__ dst, int dst_stride,
    const float* __restrict__ Wdt,  // [64][2][64] k-major
    const float* __restrict__ Wrt,  // [64][64]    k-major
    const float* __restrict__ Wst,  // [64][128]   k-major
    float* __restrict__ skip,       // [N][128][OSIZE]
    int d, int skip_init)
{
    extern __shared__ float smem[];
    const int W    = TILE + d;          // staged width per channel row
    const int Lout = Lin - d;
    const int n  = blockIdx.y;
    const int l0 = blockIdx.x * TILE;
    if (l0 >= Lout) return;
    const int np = min(TILE, Lout - l0);

    float* sx = smem;                                   // [C][W]
    // gate buffer: alias dead prefix sx[k][0:64) when d>=64, else separate
    float* sgb     = (d >= 64) ? smem : smem + C * W;
    const int sgs  = (d >= 64) ? W    : 64;             // gate row stride

    const int t    = threadIdx.x;
    const int lane = t & 63;
    const int wv   = __builtin_amdgcn_readfirstlane(t >> 6);  // wave 0..3

    // ---- stage: rows k = wv,wv+4,..; stride-1 across lanes ----
    for (int k = wv; k < C; k += 4) {
        const float* row = src + (size_t)(n * C + k) * src_stride + l0;
        float* srow = sx + k * W;
        for (int p = lane; p < W; p += 64)
            srow[p] = (l0 + p < Lin) ? row[p] : 0.f;
    }
    __syncthreads();

    const int oc0 = wv * 16;            // this wave's 16 res channels

    // ---- phase 1: dilated conv (2 taps, K=64) ----
    float acc[16];
    #pragma unroll
    for (int i = 0; i < 16; ++i) acc[i] = 0.f;
    {
        const float* sxp = sx + lane;
        for (int k = 0; k < C; ++k) {
            float a = sxp[k * W];
            float b = sxp[k * W + d];
            const float* wk = Wdt + (k << 7) + oc0;   // uniform; 16+16 contiguous
            #pragma unroll
            for (int oo = 0; oo < 16; ++oo)
                acc[oo] = fmaf(wk[oo], a, fmaf(wk[64 + oo], b, acc[oo]));
        }
    }
    __syncthreads();    // required when sg aliases sx prefix (d>=64)

    // ---- gated activation: tanh(y)*sigmoid(y) = u(u-1)/(u^2+1), u=e^y ----
    #pragma unroll
    for (int oo = 0; oo < 16; ++oo) {
        float y = fminf(fmaxf(acc[oo], -20.f), 20.f);
        float u = __expf(y);
        float g = u * (u - 1.f) / fmaf(u, u, 1.f);
        sgb[(oc0 + oo) * sgs + lane] = g;
    }
    __syncthreads();

    // ---- phase 2a: res = Wr @ g + x[:, l+d] ----
    float racc[16];
    #pragma unroll
    for (int i = 0; i < 16; ++i) racc[i] = 0.f;
    for (int k = 0; k < C; ++k) {
        float gv = sgb[k * sgs + lane];
        const float* wk = Wrt + (k << 6) + oc0;       // 16 contiguous
        #pragma unroll
        for (int oo = 0; oo < 16; ++oo)
            racc[oo] = fmaf(wk[oo], gv, racc[oo]);
    }
    if (lane < np) {
        #pragma unroll
        for (int oo = 0; oo < 16; ++oo)
            dst[(size_t)(n * C + oc0 + oo) * dst_stride + l0 + lane]
                = racc[oo] + sx[(oc0 + oo) * W + lane + d];
    }

    // ---- phase 2b: skip += Ws @ g, right-aligned [OSIZE] window ----
    const int sbase = Lout - OSIZE;     // skip slot j = l - sbase
    if (l0 + TILE > sbase) {
        const int sc0 = wv * 32;        // this wave's 32 skip channels
        float sa[32];
        #pragma unroll
        for (int i = 0; i < 32; ++i) sa[i] = 0.f;
        for (int k = 0; k < C; ++k) {
            float gv = sgb[k * sgs + lane];
            const float* wk = Wst + (k << 7) + sc0;   // 32 contiguous
            #pragma unroll
            for (int ss = 0; ss < 32; ++ss)
                sa[ss] = fmaf(wk[ss], gv, sa[ss]);
        }
        int l = l0 + lane;
        if (l >= sbase && l < Lout) {
            size_t base = (size_t)(n * SC + sc0) * OSIZE + (l - sbase);
            if (skip_init) {
                #pragma unroll
                for (int ss = 0; ss < 32; ++ss)
                    skip[base + (size_t)ss * OSIZE] = sa[ss];
            } else {
                #pragma unroll
                for (int ss = 0; ss < 32; ++ss)
                    skip[base + (size_t)ss * OSIZE] += sa[ss];
            }
        }
    }
}

extern "C" void kernel_launch(void* const* d_in, const int* in_sizes, int n_in,
                              void* d_out, int out_size, void* d_ws, size_t ws_size,
                              hipStream_t stream) {
    const float* x      = (const float*)d_in[0];
    const float* W_dil  = (const float*)d_in[1];   // [16][64][64][2]
    const float* W_res  = (const float*)d_in[2];   // [16][64][64]
    const float* W_skip = (const float*)d_in[3];   // [16][128][64]

    float* out  = (float*)d_out;                       // [16][64][7682]
    float* skip = out + (size_t)NBATCH * C * OSIZE;    // [16][128][7682]

    float* bufA = (float*)d_ws;                        // 33.6 MB
    float* bufB = bufA + (size_t)NBATCH * C * L0;      // 33.6 MB
    float* Wdt  = bufB + (size_t)NBATCH * C * L0;      // 512 KB
    float* Wrt  = Wdt + 16 * 64 * 2 * 64;              // 256 KB
    float* Wst  = Wrt + 16 * 64 * 64;                  // 512 KB

    transpose_weights<<<1280, 256, 0, stream>>>(W_dil, W_res, W_skip, Wdt, Wrt, Wst);

    const float* src = x;
    int src_stride = L0;
    int Lin = L0;
    float* bufs[2] = {bufA, bufB};

    for (int i = 0; i < 16; ++i) {
        int d    = 1 << (i & 7);
        int Lout = Lin - d;
        float* dst;
        int dst_stride;
        if (i == 15) { dst = out;         dst_stride = OSIZE; }
        else         { dst = bufs[i & 1]; dst_stride = L0;    }

        int W = TILE + d;
        size_t smem = (size_t)((d >= 64) ? C * W : C * W + C * 64) * sizeof(float);

        dim3 grid((Lout + TILE - 1) / TILE, NBATCH);
        wavenet_layer<<<grid, 256, smem, stream>>>(
            src, src_stride, Lin, dst, dst_stride,
            Wdt + (size_t)i * C * C * 2,
            Wrt + (size_t)i * C * C,
            Wst + (size_t)i * C * SC,
            skip, d, (i == 0) ? 1 : 0);

        src = dst;
        src_stride = dst_stride;
        Lin = Lout;
    }
}

// Round 5
// 634.617 us; speedup vs baseline: 4.3413x; 2.7740x over previous
//
#include <hip/hip_runtime.h>

// WaveNet residual stack — bf16 MFMA version.
//  - 16 per-layer kernels: dilated conv + gate + residual via mfma_f32_16x16x32_bf16.
//    fp32 state carried exactly (LDS fp32 copy for the residual add); only matmul
//    inputs are bf16. Gated activation g written (bf16, skip window only) to ws.
//  - One final skip GEMM: skip[s][p] = sum_{ly,k} Ws[ly][s][k] g[ly][k][p], K=1024,
//    replacing 15 read-modify-write passes (1.9 GB) with one pass (~0.3 GB).
// MFMA layouts (HW-verified per guide): A[m=lane&15][k=quad*8+j],
// B[k=quad*8+j][n=lane&15], C/D col=lane&15 row=quad*4+reg.

#define NBATCH 16
#define C 64
#define SC 128
#define L0 8192
#define OSIZE 7682
#define TILE 64

typedef __bf16 bf16x8 __attribute__((ext_vector_type(8)));
typedef __bf16 bf16x4 __attribute__((ext_vector_type(4)));
typedef float  f32x4  __attribute__((ext_vector_type(4)));

// ---- pre-pass: pack weights to bf16, k-contiguous MFMA A-layout ----
// Wdm[ly][o][kp] kp<64: tap0 ch kp ; kp>=64: tap1 ch kp-64   (16*64*128)
// Wrm[ly][o][k]                                              (16*64*64)
// Wsm[ly][s][k]                                              (16*128*64)
__global__ __launch_bounds__(256) void pack_weights(
    const float* __restrict__ Wd, const float* __restrict__ Wr,
    const float* __restrict__ Ws,
    __bf16* __restrict__ Wdm, __bf16* __restrict__ Wrm, __bf16* __restrict__ Wsm)
{
    int idx = blockIdx.x * 256 + threadIdx.x;
    if (idx < 131072) {                       // Wdm
        int kp = idx & 127, o = (idx >> 7) & 63, ly = idx >> 13;
        int k = kp & 63, tap = kp >> 6;
        Wdm[idx] = (__bf16)Wd[(((ly * 64 + o) * 64 + k) << 1) + tap];
    } else if (idx < 196608) {                // Wrm
        int j = idx - 131072;
        Wrm[j] = (__bf16)Wr[j];               // same row-major [ly][o][k]
    } else if (idx < 327680) {                // Wsm
        int j = idx - 196608;
        Wsm[j] = (__bf16)Ws[j];               // same row-major [ly][s][k]
    }
}

// ---- per-layer: conv(MFMA) + gate + res(MFMA) + g window out ----
__global__ __launch_bounds__(256) void wavenet_layer_mfma(
    const float* __restrict__ src, int src_stride, int Lin,
    float* __restrict__ dst, int dst_stride,
    const __bf16* __restrict__ Wdm,   // [64][128]
    const __bf16* __restrict__ Wrm,   // [64][64]
    __bf16* __restrict__ gout,        // [NBATCH][8][OSIZE][8] (this layer's slot)
    int d)
{
    extern __shared__ char smem_raw[];
    const int W    = TILE + d;
    const int Lout = Lin - d;
    const int n  = blockIdx.y;
    const int l0 = blockIdx.x * TILE;
    if (l0 >= Lout) return;
    const int np = min(TILE, Lout - l0);

    __bf16* sxp  = (__bf16*)smem_raw;                       // [8][W][8] k-packed
    float*  sres = (float*)(smem_raw + (size_t)8 * W * 8 * 2); // [64][65] fp32
    __bf16* sgp  = (__bf16*)(sres + 64 * 65);               // [8][64][8] k-packed

    const int t    = threadIdx.x;
    const int lane = t & 63;
    const int wv   = t >> 6;
    const int q    = lane >> 4;   // quad 0..3
    const int nn   = lane & 15;

    // ---- stage x: bf16 k-packed (+ fp32 residual window) ----
    for (int item = t; item < 8 * W; item += 256) {
        int kg = item / W;
        int p  = item % W;               // consecutive t -> consecutive p
        bool inb = (l0 + p) < Lin;
        const float* col = src + (size_t)(n * C + kg * 8) * src_stride + l0 + p;
        float v[8];
        #pragma unroll
        for (int j = 0; j < 8; ++j) v[j] = inb ? col[(size_t)j * src_stride] : 0.f;
        bf16x8 bv;
        #pragma unroll
        for (int j = 0; j < 8; ++j) bv[j] = (__bf16)v[j];
        *(bf16x8*)(sxp + ((size_t)kg * W + p) * 8) = bv;
        int pr = p - d;
        if (pr >= 0 && pr < TILE) {
            #pragma unroll
            for (int j = 0; j < 8; ++j) sres[(kg * 8 + j) * 65 + pr] = v[j];
        }
    }
    __syncthreads();

    // ---- phase 1: y = Wd0@x_l + Wd1@x_r (K'=128, 4 ksteps), gate -> sgp ----
    const __bf16* arow = Wdm + (size_t)(wv * 16 + nn) * 128 + q * 8;
    bf16x8 aW[4];
    #pragma unroll
    for (int ks = 0; ks < 4; ++ks) aW[ks] = *(const bf16x8*)(arow + ks * 32);

    #pragma unroll
    for (int nt = 0; nt < 4; ++nt) {
        int p0 = nt * 16;
        f32x4 acc = {0.f, 0.f, 0.f, 0.f};
        acc = __builtin_amdgcn_mfma_f32_16x16x32_bf16(aW[0],
                *(const bf16x8*)(sxp + ((size_t)(q    ) * W + p0 + nn    ) * 8), acc, 0, 0, 0);
        acc = __builtin_amdgcn_mfma_f32_16x16x32_bf16(aW[1],
                *(const bf16x8*)(sxp + ((size_t)(4 + q) * W + p0 + nn    ) * 8), acc, 0, 0, 0);
        acc = __builtin_amdgcn_mfma_f32_16x16x32_bf16(aW[2],
                *(const bf16x8*)(sxp + ((size_t)(q    ) * W + p0 + nn + d) * 8), acc, 0, 0, 0);
        acc = __builtin_amdgcn_mfma_f32_16x16x32_bf16(aW[3],
                *(const bf16x8*)(sxp + ((size_t)(4 + q) * W + p0 + nn + d) * 8), acc, 0, 0, 0);
        // gate: tanh(y)*sigmoid(y) = u(u-1)/(u^2+1), u=e^y
        bf16x4 gv;
        #pragma unroll
        for (int r = 0; r < 4; ++r) {
            float y = fminf(fmaxf(acc[r], -20.f), 20.f);
            float u = __expf(y);
            gv[r] = (__bf16)(u * (u - 1.f) / fmaf(u, u, 1.f));
        }
        // ch = wv*16 + q*4 + r -> kgrp = 2wv + (q>>1), slot (q&1)*4+r : one b64 write
        *(bf16x4*)(sgp + ((size_t)(2 * wv + (q >> 1)) * 64 + p0 + nn) * 8 + (q & 1) * 4) = gv;
    }
    __syncthreads();

    // ---- phase 2a: res = Wr@g + x[:, l+d] (fp32 state) ----
    const __bf16* rrow = Wrm + (size_t)(wv * 16 + nn) * 64 + q * 8;
    bf16x8 aR0 = *(const bf16x8*)rrow;
    bf16x8 aR1 = *(const bf16x8*)(rrow + 32);
    #pragma unroll
    for (int nt = 0; nt < 4; ++nt) {
        int p0 = nt * 16;
        f32x4 acc = {0.f, 0.f, 0.f, 0.f};
        acc = __builtin_amdgcn_mfma_f32_16x16x32_bf16(aR0,
                *(const bf16x8*)(sgp + ((size_t)(q    ) * 64 + p0 + nn) * 8), acc, 0, 0, 0);
        acc = __builtin_amdgcn_mfma_f32_16x16x32_bf16(aR1,
                *(const bf16x8*)(sgp + ((size_t)(4 + q) * 64 + p0 + nn) * 8), acc, 0, 0, 0);
        if (p0 + nn < np) {
            #pragma unroll
            for (int r = 0; r < 4; ++r) {
                int ch = wv * 16 + q * 4 + r;
                dst[(size_t)(n * C + ch) * dst_stride + l0 + p0 + nn]
                    = acc[r] + sres[ch * 65 + p0 + nn];
            }
        }
    }

    // ---- write g window (bf16, coalesced b128) for the final skip GEMM ----
    const int sbase = Lout - OSIZE;
    for (int item = t; item < 8 * TILE; item += 256) {
        int p  = item & 63;
        int kg = item >> 6;
        int l  = l0 + p;
        if (l >= sbase && l < Lout) {
            size_t j = (size_t)(l - sbase);
            *(bf16x8*)(gout + (((size_t)n * 8 + kg) * OSIZE + j) * 8)
                = *(const bf16x8*)(sgp + ((size_t)kg * 64 + p) * 8);
        }
    }
}

// ---- final: skip = sum over G layers of Ws@g  (K = G*64) ----
__global__ __launch_bounds__(256) void skip_gemm(
    const __bf16* __restrict__ g,     // [G][NBATCH][8][OSIZE][8]
    const __bf16* __restrict__ Wsm,   // [16][128][64]
    float* __restrict__ skip,         // [NBATCH][128][OSIZE]
    int G, int lybase, int init)
{
    const int n  = blockIdx.y;
    const int l0 = blockIdx.x * TILE;
    const int t  = threadIdx.x;
    const int lane = t & 63, wv = t >> 6, q = lane >> 4, nn = lane & 15;

    f32x4 acc[2][4];
    #pragma unroll
    for (int mt = 0; mt < 2; ++mt)
        #pragma unroll
        for (int nt = 0; nt < 4; ++nt) acc[mt][nt] = (f32x4){0.f, 0.f, 0.f, 0.f};

    for (int gi = 0; gi < G; ++gi) {
        const __bf16* Wl = Wsm + (size_t)(lybase + gi) * SC * 64;
        const __bf16* gl = g + ((size_t)gi * NBATCH + n) * 8 * OSIZE * 8;
        #pragma unroll
        for (int ks = 0; ks < 2; ++ks) {
            bf16x8 a0 = *(const bf16x8*)(Wl + (size_t)(wv * 32 +      nn) * 64 + ks * 32 + q * 8);
            bf16x8 a1 = *(const bf16x8*)(Wl + (size_t)(wv * 32 + 16 + nn) * 64 + ks * 32 + q * 8);
            #pragma unroll
            for (int nt = 0; nt < 4; ++nt) {
                int pc = l0 + nt * 16 + nn;
                if (pc > OSIZE - 1) pc = OSIZE - 1;       // clamp OOB (masked at store)
                bf16x8 b = *(const bf16x8*)(gl + (((size_t)(ks * 4 + q)) * OSIZE + pc) * 8);
                acc[0][nt] = __builtin_amdgcn_mfma_f32_16x16x32_bf16(a0, b, acc[0][nt], 0, 0, 0);
                acc[1][nt] = __builtin_amdgcn_mfma_f32_16x16x32_bf16(a1, b, acc[1][nt], 0, 0, 0);
            }
        }
    }
    #pragma unroll
    for (int mt = 0; mt < 2; ++mt)
        #pragma unroll
        for (int nt = 0; nt < 4; ++nt) {
            int p = l0 + nt * 16 + nn;
            if (p < OSIZE) {
                #pragma unroll
                for (int r = 0; r < 4; ++r) {
                    int s = wv * 32 + mt * 16 + q * 4 + r;
                    size_t idx = ((size_t)n * SC + s) * OSIZE + p;
                    float v = acc[mt][nt][r];
                    skip[idx] = init ? v : (skip[idx] + v);
                }
            }
        }
}

extern "C" void kernel_launch(void* const* d_in, const int* in_sizes, int n_in,
                              void* d_out, int out_size, void* d_ws, size_t ws_size,
                              hipStream_t stream) {
    const float* x      = (const float*)d_in[0];
    const float* W_dil  = (const float*)d_in[1];
    const float* W_res  = (const float*)d_in[2];
    const float* W_skip = (const float*)d_in[3];

    float* out  = (float*)d_out;                        // [16][64][7682]
    float* skip = out + (size_t)NBATCH * C * OSIZE;     // [16][128][7682]

    float*  bufA = (float*)d_ws;
    float*  bufB = bufA + (size_t)NBATCH * C * L0;
    __bf16* Wdm  = (__bf16*)(bufB + (size_t)NBATCH * C * L0);
    __bf16* Wrm  = Wdm + 16 * 64 * 128;
    __bf16* Wsm  = Wrm + 16 * 64 * 64;
    __bf16* gst  = Wsm + 16 * 128 * 64;                 // g slots start here

    const size_t slotHW = (size_t)NBATCH * 8 * OSIZE * 8;   // halfwords per layer slot
    const size_t used   = (size_t)((char*)gst - (char*)d_ws);
    int G = 16;
    while (G > 1 && used + (size_t)G * slotHW * 2 > ws_size) G >>= 1;

    pack_weights<<<1280, 256, 0, stream>>>(W_dil, W_res, W_skip, Wdm, Wrm, Wsm);

    const float* src = x;
    int src_stride = L0, Lin = L0;
    float* bufs[2] = {bufA, bufB};

    for (int i = 0; i < 16; ++i) {
        int d    = 1 << (i & 7);
        int Lout = Lin - d;
        float* dst;
        int dst_stride;
        if (i == 15) { dst = out;         dst_stride = OSIZE; }
        else         { dst = bufs[i & 1]; dst_stride = L0;    }

        int W = TILE + d;
        size_t smem = (size_t)128 * W + 64 * 65 * 4 + 8 * 64 * 8 * 2;

        dim3 grid((Lout + TILE - 1) / TILE, NBATCH);
        wavenet_layer_mfma<<<grid, 256, smem, stream>>>(
            src, src_stride, Lin, dst, dst_stride,
            Wdm + (size_t)i * 64 * 128,
            Wrm + (size_t)i * 64 * 64,
            gst + (size_t)(i % G) * slotHW,
            d);

        if (((i + 1) % G) == 0) {
            dim3 sgrid((OSIZE + TILE - 1) / TILE, NBATCH);
            skip_gemm<<<sgrid, 256, 0, stream>>>(
                gst, Wsm, skip, G, i + 1 - G, (i + 1 == G) ? 1 : 0);
        }

        src = dst;
        src_stride = dst_stride;
        Lin = Lout;
    }
}